// Round 1
// baseline (560.296 us; speedup 1.0000x reference)
//
#include <hip/hip_runtime.h>
#include <math.h>

// Problem constants
// B=4096, MBITS=64, P=64, FREQ=16, BLK=8, KS=5, SIGMA=1
#define BATCH 4096

// ---------------------------------------------------------------------------
// Tiled fp32 GEMM with fused bias + activation.
// C[m, n] = act( sum_k A[m,k] * B[k,n] + bias[n] ),  C row pitch = ldc
// ACT: 0 = relu, 1 = tanh
// Tile: 64x64, TILE_K=16, 256 threads, 4x4 micro-tile per thread.
// Requires: M%64==0, N%64==0, K%16==0 (true for all 5 GEMMs here).
// ---------------------------------------------------------------------------
template <int ACT>
__global__ __launch_bounds__(256) void gemm_act(
    const float* __restrict__ A, const float* __restrict__ B,
    const float* __restrict__ bias, float* __restrict__ C,
    int M, int N, int K, int ldc) {
  // As padded to 68 floats/row: 272B row pitch keeps 16B alignment for b128
  // reads and breaks store bank conflicts.
  __shared__ float As[16][68];  // [k][m]
  __shared__ float Bs[16][64];  // [k][n]

  const int t = threadIdx.x;
  const int bm = blockIdx.x * 64;
  const int bn = blockIdx.y * 64;
  const int tx = t & 15;  // n group
  const int ty = t >> 4;  // m group

  float acc[4][4] = {};

  for (int k0 = 0; k0 < K; k0 += 16) {
    // --- load A tile (64 m x 16 k), float4 along k, transpose into As[k][m]
    {
      const int m = t >> 2;   // 0..63
      const int kq = t & 3;   // 0..3
      const float4 av =
          *reinterpret_cast<const float4*>(&A[(size_t)(bm + m) * K + k0 + kq * 4]);
      As[kq * 4 + 0][m] = av.x;
      As[kq * 4 + 1][m] = av.y;
      As[kq * 4 + 2][m] = av.z;
      As[kq * 4 + 3][m] = av.w;
    }
    // --- load B tile (16 k x 64 n), float4 along n
    {
      const int k = t >> 4;   // 0..15
      const int nq = t & 15;  // 0..15
      const float4 bv =
          *reinterpret_cast<const float4*>(&B[(size_t)(k0 + k) * N + bn + nq * 4]);
      *reinterpret_cast<float4*>(&Bs[k][nq * 4]) = bv;
    }
    __syncthreads();

#pragma unroll
    for (int kk = 0; kk < 16; ++kk) {
      float a[4], b[4];
#pragma unroll
      for (int i = 0; i < 4; ++i) a[i] = As[kk][ty * 4 + i];
#pragma unroll
      for (int j = 0; j < 4; ++j) b[j] = Bs[kk][tx * 4 + j];
#pragma unroll
      for (int i = 0; i < 4; ++i)
#pragma unroll
        for (int j = 0; j < 4; ++j) acc[i][j] += a[i] * b[j];
    }
    __syncthreads();
  }

#pragma unroll
  for (int i = 0; i < 4; ++i) {
    const int m = bm + ty * 4 + i;
#pragma unroll
    for (int j = 0; j < 4; ++j) {
      const int n = bn + tx * 4 + j;
      float v = acc[i][j] + bias[n];
      if (ACT == 0)
        v = fmaxf(v, 0.0f);
      else
        v = tanhf(v);
      C[(size_t)m * ldc + n] = v;
    }
  }
}

// ---------------------------------------------------------------------------
// Finalize: per batch image, build the 3 channels (spatial already resident in
// d_out channel 0; freq via bilinear upsample of the 16x16 map; block from the
// message bits) and apply the separable 5x5 Gaussian, writing [3,64,64].
// ---------------------------------------------------------------------------
__global__ __launch_bounds__(256) void finalize_kernel(
    const float* __restrict__ msg,      // [B,64]
    const float* __restrict__ freq_lo,  // [B,256] (16x16 row-major)
    float* __restrict__ out)            // [B,3,64,64]
{
  const int b = blockIdx.x;
  const int t = threadIdx.x;

  __shared__ float chan[64][64];
  __shared__ float tmp[64][64];
  __shared__ float fl[16][16];
  __shared__ float msgs[64];
  __shared__ int lo_tab[64];
  __shared__ float w_tab[64];

  // Gaussian 1D taps (normalized; outer-product form == separable passes)
  const float g0 = 0.054488684549644346f;  // e^-2 / sum
  const float g1 = 0.24420134200323332f;   // e^-0.5 / sum
  const float g2 = 0.4026199468907953f;    // 1 / sum
  const float g[5] = {g0, g1, g2, g1, g0};

  if (t < 64) {
    msgs[t] = msg[(size_t)b * 64 + t];
    const float pos = (float)t * (15.0f / 63.0f);
    int lo = (int)floorf(pos);
    if (lo > 15) lo = 15;
    lo_tab[t] = lo;
    w_tab[t] = pos - (float)lo;
  }
  if (t < 256) {
    fl[t >> 4][t & 15] = freq_lo[(size_t)b * 256 + t];
  }
  __syncthreads();

  const size_t out_base = (size_t)b * 3 * 4096;

  for (int c = 0; c < 3; ++c) {
    // ---- build channel into LDS
    for (int i = t; i < 4096; i += 256) {
      const int p = i >> 6;
      const int q = i & 63;
      float v;
      if (c == 0) {
        v = out[out_base + i];  // spatial (written by GEMM3 epilogue)
      } else if (c == 1) {
        const int lp = lo_tab[p], lq = lo_tab[q];
        const int hp = lp < 15 ? lp + 1 : 15;
        const int hq = lq < 15 ? lq + 1 : 15;
        const float wp = w_tab[p], wq = w_tab[q];
        const float v00 = fl[lp][lq], v01 = fl[lp][hq];
        const float v10 = fl[hp][lq], v11 = fl[hp][hq];
        v = (1.0f - wp) * ((1.0f - wq) * v00 + wq * v01) +
            wp * ((1.0f - wq) * v10 + wq * v11);
      } else {
        v = msgs[((p >> 3) << 3) + (q >> 3)];
      }
      chan[p][q] = v;
    }
    __syncthreads();

    // ---- horizontal pass (zero padding)
    for (int i = t; i < 4096; i += 256) {
      const int p = i >> 6;
      const int q = i & 63;
      float s = 0.0f;
#pragma unroll
      for (int d = -2; d <= 2; ++d) {
        const int qq = q + d;
        if (qq >= 0 && qq < 64) s += g[d + 2] * chan[p][qq];
      }
      tmp[p][q] = s;
    }
    __syncthreads();

    // ---- vertical pass + store
    for (int i = t; i < 4096; i += 256) {
      const int p = i >> 6;
      const int q = i & 63;
      float s = 0.0f;
#pragma unroll
      for (int d = -2; d <= 2; ++d) {
        const int pp = p + d;
        if (pp >= 0 && pp < 64) s += g[d + 2] * tmp[pp][q];
      }
      out[out_base + (size_t)c * 4096 + i] = s;
    }
    __syncthreads();  // protect chan/tmp before next channel reuses them
  }
}

// ---------------------------------------------------------------------------
extern "C" void kernel_launch(void* const* d_in, const int* in_sizes, int n_in,
                              void* d_out, int out_size, void* d_ws,
                              size_t ws_size, hipStream_t stream) {
  const float* msg = (const float*)d_in[0];
  const float* sW1 = (const float*)d_in[1];
  const float* sb1 = (const float*)d_in[2];
  const float* sW2 = (const float*)d_in[3];
  const float* sb2 = (const float*)d_in[4];
  const float* sW3 = (const float*)d_in[5];
  const float* sb3 = (const float*)d_in[6];
  const float* fW1 = (const float*)d_in[7];
  const float* fb1 = (const float*)d_in[8];
  const float* fW2 = (const float*)d_in[9];
  const float* fb2 = (const float*)d_in[10];

  float* out = (float*)d_out;
  float* ws = (float*)d_ws;

  float* h1 = ws;                    // 4096*256
  float* h2 = h1 + BATCH * 256;      // 4096*512
  float* f1 = h2 + BATCH * 512;      // 4096*128
  float* fl = f1 + BATCH * 128;      // 4096*256
  // total ws use: 4096*1152*4 B = 18.9 MB

  const dim3 blk(256);

  // spatial MLP
  gemm_act<0><<<dim3(64, 4), blk, 0, stream>>>(msg, sW1, sb1, h1, BATCH, 256, 64, 256);
  gemm_act<0><<<dim3(64, 8), blk, 0, stream>>>(h1, sW2, sb2, h2, BATCH, 512, 256, 512);
  // tanh(spatial) straight into d_out channel 0 (row pitch 3*4096)
  gemm_act<1><<<dim3(64, 64), blk, 0, stream>>>(h2, sW3, sb3, out, BATCH, 4096, 512, 12288);

  // frequency MLP
  gemm_act<0><<<dim3(64, 2), blk, 0, stream>>>(msg, fW1, fb1, f1, BATCH, 128, 64, 128);
  gemm_act<1><<<dim3(64, 4), blk, 0, stream>>>(f1, fW2, fb2, fl, BATCH, 256, 128, 256);

  // upsample + block pattern + depthwise Gaussian
  finalize_kernel<<<dim3(BATCH), blk, 0, stream>>>(msg, fl, out);
}

// Round 2
// 356.533 us; speedup vs baseline: 1.5715x; 1.5715x over previous
//
#include <hip/hip_runtime.h>
#include <math.h>

#define BATCH 4096

typedef __attribute__((ext_vector_type(8))) short short8;
typedef __attribute__((ext_vector_type(4))) float f32x4;

__device__ __forceinline__ unsigned short f2bf(float f) {
  unsigned int u = __float_as_uint(f);
  u += 0x7FFF + ((u >> 16) & 1);  // RNE
  return (unsigned short)(u >> 16);
}

#define GLL16(g, l)                                                    \
  __builtin_amdgcn_global_load_lds(                                    \
      (const __attribute__((address_space(1))) unsigned int*)(g),      \
      (__attribute__((address_space(3))) unsigned int*)(l), 16, 0, 0)

// ---------------------------------------------------------------------------
// fp32 tiled GEMM with fused bias + activation (small layers).
// ACT: 0 = relu, 1 = tanh.  OBF16: store bf16 instead of fp32.
// Tile 64x64, TILE_K=16, 256 threads, 4x4 per thread.
// ---------------------------------------------------------------------------
template <int ACT, int OBF16>
__global__ __launch_bounds__(256) void gemm_act(
    const float* __restrict__ A, const float* __restrict__ B,
    const float* __restrict__ bias, void* __restrict__ Cv,
    int M, int N, int K, int ldc) {
  __shared__ float As[16][68];
  __shared__ float Bs[16][64];

  const int t = threadIdx.x;
  const int bm = blockIdx.x * 64;
  const int bn = blockIdx.y * 64;
  const int tx = t & 15;
  const int ty = t >> 4;

  float acc[4][4] = {};

  for (int k0 = 0; k0 < K; k0 += 16) {
    {
      const int m = t >> 2;
      const int kq = t & 3;
      const float4 av =
          *reinterpret_cast<const float4*>(&A[(size_t)(bm + m) * K + k0 + kq * 4]);
      As[kq * 4 + 0][m] = av.x;
      As[kq * 4 + 1][m] = av.y;
      As[kq * 4 + 2][m] = av.z;
      As[kq * 4 + 3][m] = av.w;
    }
    {
      const int k = t >> 4;
      const int nq = t & 15;
      const float4 bv =
          *reinterpret_cast<const float4*>(&B[(size_t)(k0 + k) * N + bn + nq * 4]);
      *reinterpret_cast<float4*>(&Bs[k][nq * 4]) = bv;
    }
    __syncthreads();

#pragma unroll
    for (int kk = 0; kk < 16; ++kk) {
      float a[4], b[4];
#pragma unroll
      for (int i = 0; i < 4; ++i) a[i] = As[kk][ty * 4 + i];
#pragma unroll
      for (int j = 0; j < 4; ++j) b[j] = Bs[kk][tx * 4 + j];
#pragma unroll
      for (int i = 0; i < 4; ++i)
#pragma unroll
        for (int j = 0; j < 4; ++j) acc[i][j] += a[i] * b[j];
    }
    __syncthreads();
  }

#pragma unroll
  for (int i = 0; i < 4; ++i) {
    const int m = bm + ty * 4 + i;
#pragma unroll
    for (int j = 0; j < 4; ++j) {
      const int n = bn + tx * 4 + j;
      float v = acc[i][j] + bias[n];
      if (ACT == 0)
        v = fmaxf(v, 0.0f);
      else
        v = tanhf(v);
      if (OBF16)
        ((unsigned short*)Cv)[(size_t)m * ldc + n] = f2bf(v);
      else
        ((float*)Cv)[(size_t)m * ldc + n] = v;
    }
  }
}

// ---------------------------------------------------------------------------
// Transpose + convert sW3: fp32 [512][4096] -> bf16 [4096][512]
// ---------------------------------------------------------------------------
__global__ __launch_bounds__(256) void transpose_w3(
    const float* __restrict__ W, unsigned short* __restrict__ WT) {
  __shared__ float tile[32][33];
  const int bx = blockIdx.x;  // n tile (0..127)
  const int by = blockIdx.y;  // k tile (0..15)
  const int t = threadIdx.x;
  {
    const int r = t >> 3, c4 = (t & 7) * 4;
    const float4 v =
        *reinterpret_cast<const float4*>(&W[(size_t)(by * 32 + r) * 4096 + bx * 32 + c4]);
    tile[r][c4 + 0] = v.x;
    tile[r][c4 + 1] = v.y;
    tile[r][c4 + 2] = v.z;
    tile[r][c4 + 3] = v.w;
  }
  __syncthreads();
  {
    const int nl = t >> 3, k4 = (t & 7) * 4;
    unsigned short o[4];
#pragma unroll
    for (int i = 0; i < 4; ++i) o[i] = f2bf(tile[k4 + i][nl]);
    *reinterpret_cast<ushort4*>(&WT[(size_t)(bx * 32 + nl) * 512 + by * 32 + k4]) =
        *reinterpret_cast<const ushort4*>(o);
  }
}

// ---------------------------------------------------------------------------
// GEMM3: C = tanh(A @ B + bias), A bf16 [4096][512], B given transposed bf16
// [4096][512]; out fp32 with row pitch 12288 (d_out channel 0).
// 128x128 tile, BK=32, 4 waves, mfma_f32_16x16x32_bf16,
// global_load_lds(16B) staging with XOR swizzle (chunk ^= (row>>1)&3).
// ---------------------------------------------------------------------------
__global__ __launch_bounds__(256) void gemm3_mfma(
    const unsigned short* __restrict__ A, const unsigned short* __restrict__ BT,
    const float* __restrict__ bias, float* __restrict__ out) {
  __shared__ __align__(16) unsigned short As[128 * 32];
  __shared__ __align__(16) unsigned short Bs[128 * 32];

  const int t = threadIdx.x;
  const int lane = t & 63;
  const int w = t >> 6;
  const int bm = blockIdx.x * 128;
  const int bn = blockIdx.y * 128;

  // staging: wave w issues loads u=2w,2w+1 for A and B; load u covers tile
  // rows 16u..16u+15; lane l -> r = 16u + (l>>2), swizzled chunk c' = l&3,
  // data chunk c = c' ^ ((r>>1)&3)
  const int r0 = w * 32 + (lane >> 2);
  const int r1 = r0 + 16;
  const int c0 = (lane & 3) ^ ((r0 >> 1) & 3);
  const int c1 = (lane & 3) ^ ((r1 >> 1) & 3);

  const unsigned short* gA0 = A + (size_t)(bm + r0) * 512 + c0 * 8;
  const unsigned short* gA1 = A + (size_t)(bm + r1) * 512 + c1 * 8;
  const unsigned short* gB0 = BT + (size_t)(bn + r0) * 512 + c0 * 8;
  const unsigned short* gB1 = BT + (size_t)(bn + r1) * 512 + c1 * 8;

  unsigned short* lA0 = &As[(w * 2 + 0) * 512];
  unsigned short* lA1 = &As[(w * 2 + 1) * 512];
  unsigned short* lB0 = &Bs[(w * 2 + 0) * 512];
  unsigned short* lB1 = &Bs[(w * 2 + 1) * 512];

  // fragment read offsets (short units), constant across K-steps
  const int wm = (w >> 1) * 64;
  const int wn = (w & 1) * 64;
  const int lr = lane & 15;
  const int lc = lane >> 4;
  int aoff[4], boff[4];
#pragma unroll
  for (int i = 0; i < 4; ++i) {
    const int row = wm + i * 16 + lr;
    aoff[i] = row * 32 + (lc ^ ((row >> 1) & 3)) * 8;
    const int col = wn + i * 16 + lr;
    boff[i] = col * 32 + (lc ^ ((col >> 1) & 3)) * 8;
  }

  f32x4 acc[4][4];
  const f32x4 z = {0.f, 0.f, 0.f, 0.f};
#pragma unroll
  for (int i = 0; i < 4; ++i)
#pragma unroll
    for (int j = 0; j < 4; ++j) acc[i][j] = z;

  for (int kt = 0; kt < 16; ++kt) {
    GLL16(gA0, lA0);
    GLL16(gA1, lA1);
    GLL16(gB0, lB0);
    GLL16(gB1, lB1);
    __syncthreads();  // compiler drains vmcnt before barrier

    short8 a[4], b[4];
#pragma unroll
    for (int i = 0; i < 4; ++i) a[i] = *reinterpret_cast<const short8*>(&As[aoff[i]]);
#pragma unroll
    for (int j = 0; j < 4; ++j) b[j] = *reinterpret_cast<const short8*>(&Bs[boff[j]]);

#pragma unroll
    for (int i = 0; i < 4; ++i)
#pragma unroll
      for (int j = 0; j < 4; ++j)
        acc[i][j] =
            __builtin_amdgcn_mfma_f32_16x16x32_bf16(a[i], b[j], acc[i][j], 0, 0, 0);

    __syncthreads();  // protect LDS before next stage
    gA0 += 32; gA1 += 32; gB0 += 32; gB1 += 32;
  }

  // epilogue: C/D layout col = lane&15, row = (lane>>4)*4 + reg
  const int base_row = bm + wm + ((lane >> 4) << 2);
  const int base_col = bn + wn + lr;
#pragma unroll
  for (int i = 0; i < 4; ++i) {
#pragma unroll
    for (int j = 0; j < 4; ++j) {
      const int n = base_col + j * 16;
      const float bv = bias[n];
#pragma unroll
      for (int r = 0; r < 4; ++r) {
        const int m = base_row + i * 16 + r;
        out[(size_t)m * 12288 + n] = tanhf(acc[i][j][r] + bv);
      }
    }
  }
}

// ---------------------------------------------------------------------------
// Finalize: one block per (batch, channel). Build channel in LDS, separable
// 5x5 Gaussian, write [64,64] fp32.
// ---------------------------------------------------------------------------
__global__ __launch_bounds__(256) void finalize_kernel(
    const float* __restrict__ msg, const float* __restrict__ freq_lo,
    float* __restrict__ out) {
  const int b = blockIdx.x;
  const int c = blockIdx.y;
  const int t = threadIdx.x;

  __shared__ float chan[4096];
  __shared__ float tmp[4096];
  __shared__ float fl[256];
  __shared__ float msgs[64];
  __shared__ int lo_tab[64];
  __shared__ float w_tab[64];

  const float g0 = 0.054488684549644346f;
  const float g1 = 0.24420134200323332f;
  const float g2 = 0.4026199468907953f;
  const float g[5] = {g0, g1, g2, g1, g0};

  if (t < 64) {
    msgs[t] = msg[(size_t)b * 64 + t];
    const float pos = (float)t * (15.0f / 63.0f);
    int lo = (int)floorf(pos);
    if (lo > 15) lo = 15;
    lo_tab[t] = lo;
    w_tab[t] = pos - (float)lo;
  }
  fl[t] = freq_lo[(size_t)b * 256 + t];
  __syncthreads();

  const size_t out_base = (size_t)b * 12288;

  if (c == 0) {
    const float4* src = reinterpret_cast<const float4*>(out + out_base);
    float4* dst = reinterpret_cast<float4*>(chan);
    for (int i = t; i < 1024; i += 256) dst[i] = src[i];
  } else if (c == 1) {
    for (int i = t; i < 4096; i += 256) {
      const int p = i >> 6, q = i & 63;
      const int lp = lo_tab[p], lq = lo_tab[q];
      const int hp = lp < 15 ? lp + 1 : 15;
      const int hq = lq < 15 ? lq + 1 : 15;
      const float wp = w_tab[p], wq = w_tab[q];
      const float v00 = fl[lp * 16 + lq], v01 = fl[lp * 16 + hq];
      const float v10 = fl[hp * 16 + lq], v11 = fl[hp * 16 + hq];
      chan[i] = (1.0f - wp) * ((1.0f - wq) * v00 + wq * v01) +
                wp * ((1.0f - wq) * v10 + wq * v11);
    }
  } else {
    for (int i = t; i < 4096; i += 256) {
      const int p = i >> 6, q = i & 63;
      chan[i] = msgs[((p >> 3) << 3) + (q >> 3)];
    }
  }
  __syncthreads();

  for (int i = t; i < 4096; i += 256) {
    const int p = i >> 6, q = i & 63;
    float s = 0.0f;
#pragma unroll
    for (int d = -2; d <= 2; ++d) {
      const int qq = q + d;
      if (qq >= 0 && qq < 64) s += g[d + 2] * chan[p * 64 + qq];
    }
    tmp[i] = s;
  }
  __syncthreads();

  float4* dst = reinterpret_cast<float4*>(out + out_base + (size_t)c * 4096);
  for (int i = t; i < 1024; i += 256) {
    const int p = i >> 4;
    const int q4 = (i & 15) * 4;
    float s0 = 0.f, s1 = 0.f, s2 = 0.f, s3 = 0.f;
#pragma unroll
    for (int d = -2; d <= 2; ++d) {
      const int pp = p + d;
      if (pp >= 0 && pp < 64) {
        const float gg = g[d + 2];
        const int base = pp * 64 + q4;
        s0 += gg * tmp[base + 0];
        s1 += gg * tmp[base + 1];
        s2 += gg * tmp[base + 2];
        s3 += gg * tmp[base + 3];
      }
    }
    float4 v;
    v.x = s0; v.y = s1; v.z = s2; v.w = s3;
    dst[i] = v;
  }
}

// ---------------------------------------------------------------------------
extern "C" void kernel_launch(void* const* d_in, const int* in_sizes, int n_in,
                              void* d_out, int out_size, void* d_ws,
                              size_t ws_size, hipStream_t stream) {
  const float* msg = (const float*)d_in[0];
  const float* sW1 = (const float*)d_in[1];
  const float* sb1 = (const float*)d_in[2];
  const float* sW2 = (const float*)d_in[3];
  const float* sb2 = (const float*)d_in[4];
  const float* sW3 = (const float*)d_in[5];
  const float* sb3 = (const float*)d_in[6];
  const float* fW1 = (const float*)d_in[7];
  const float* fb1 = (const float*)d_in[8];
  const float* fW2 = (const float*)d_in[9];
  const float* fb2 = (const float*)d_in[10];

  float* out = (float*)d_out;
  char* wsb = (char*)d_ws;

  float* h1 = (float*)(wsb);                              // 4 MB
  unsigned short* h2 = (unsigned short*)(wsb + (4 << 20));  // 4 MB bf16
  unsigned short* w3T = (unsigned short*)(wsb + (8 << 20)); // 4 MB bf16
  float* f1 = (float*)(wsb + (12 << 20));                 // 2 MB
  float* fl = (float*)(wsb + (14 << 20));                 // 4 MB

  const dim3 blk(256);

  transpose_w3<<<dim3(128, 16), blk, 0, stream>>>(sW3, w3T);

  // spatial MLP
  gemm_act<0, 0><<<dim3(64, 4), blk, 0, stream>>>(msg, sW1, sb1, h1, BATCH, 256, 64, 256);
  gemm_act<0, 1><<<dim3(64, 8), blk, 0, stream>>>(h1, sW2, sb2, h2, BATCH, 512, 256, 512);
  gemm3_mfma<<<dim3(32, 32), blk, 0, stream>>>(h2, w3T, sb3, out);

  // frequency MLP
  gemm_act<0, 0><<<dim3(64, 2), blk, 0, stream>>>(msg, fW1, fb1, f1, BATCH, 128, 64, 128);
  gemm_act<1, 0><<<dim3(64, 4), blk, 0, stream>>>(f1, fW2, fb2, fl, BATCH, 256, 128, 256);

  // upsample + block pattern + depthwise Gaussian
  finalize_kernel<<<dim3(BATCH, 3), blk, 0, stream>>>(msg, fl, out);
}

// Round 4
// 345.246 us; speedup vs baseline: 1.6229x; 1.0327x over previous
//
#include <hip/hip_runtime.h>
#include <math.h>

#define BATCH 4096

typedef __attribute__((ext_vector_type(8))) short short8;
typedef __attribute__((ext_vector_type(4))) float f32x4;

__device__ __forceinline__ unsigned short f2bf(float f) {
  unsigned int u = __float_as_uint(f);
  u += 0x7FFF + ((u >> 16) & 1);  // RNE
  return (unsigned short)(u >> 16);
}

__device__ __forceinline__ float bf2f(unsigned short s) {
  return __uint_as_float(((unsigned int)s) << 16);
}

__device__ __forceinline__ float fast_tanh(float x) {
  // tanh(x) = 1 - 2/(exp(2x)+1); exp via v_exp_f32, rcp via v_rcp_f32.
  const float e = __expf(2.0f * x);
  const float r = __builtin_amdgcn_rcpf(e + 1.0f);
  return fmaf(-2.0f, r, 1.0f);
}

#define GLL16(g, l)                                                    \
  __builtin_amdgcn_global_load_lds(                                    \
      (const __attribute__((address_space(1))) unsigned int*)(g),      \
      (__attribute__((address_space(3))) unsigned int*)(l), 16, 0, 0)

// ---------------------------------------------------------------------------
// prep: transpose+convert sW1/sW2/sW3 (fp32 [K][N]) -> bf16 [N][K], and
// convert msg -> bf16. Tile 32x32 per block; msg blocks convert 2048 elems.
// grid = 16 + 128 + 2048 + 128 = 2320 blocks.
// ---------------------------------------------------------------------------
__global__ __launch_bounds__(256) void prep_kernel(
    const float* __restrict__ sW1, const float* __restrict__ sW2,
    const float* __restrict__ sW3, const float* __restrict__ msg,
    unsigned short* __restrict__ w1T, unsigned short* __restrict__ w2T,
    unsigned short* __restrict__ w3T, unsigned short* __restrict__ msgb) {
  const int b = blockIdx.x;
  const int t = threadIdx.x;

  if (b >= 2192) {  // msg convert: 128 blocks x 2048 floats
    const int i0 = (b - 2192) * 2048 + t * 8;
    const float4 v0 = *reinterpret_cast<const float4*>(&msg[i0]);
    const float4 v1 = *reinterpret_cast<const float4*>(&msg[i0 + 4]);
    short8 o;
    o[0] = (short)f2bf(v0.x); o[1] = (short)f2bf(v0.y);
    o[2] = (short)f2bf(v0.z); o[3] = (short)f2bf(v0.w);
    o[4] = (short)f2bf(v1.x); o[5] = (short)f2bf(v1.y);
    o[6] = (short)f2bf(v1.z); o[7] = (short)f2bf(v1.w);
    *reinterpret_cast<short8*>(&msgb[i0]) = o;
    return;
  }

  const float* src;
  unsigned short* dst;
  int K, N, lgtN, tile;
  if (b < 16) {
    src = sW1; dst = w1T; K = 64; N = 256; lgtN = 3; tile = b;
  } else if (b < 144) {
    src = sW2; dst = w2T; K = 256; N = 512; lgtN = 4; tile = b - 16;
  } else {
    src = sW3; dst = w3T; K = 512; N = 4096; lgtN = 7; tile = b - 144;
  }
  const int ty = tile >> lgtN;          // k tile
  const int tx = tile & ((1 << lgtN) - 1);  // n tile

  __shared__ float tl[32][33];
  {
    const int r = t >> 3, c4 = (t & 7) * 4;
    const float4 v =
        *reinterpret_cast<const float4*>(&src[(size_t)(ty * 32 + r) * N + tx * 32 + c4]);
    tl[r][c4 + 0] = v.x; tl[r][c4 + 1] = v.y;
    tl[r][c4 + 2] = v.z; tl[r][c4 + 3] = v.w;
  }
  __syncthreads();
  {
    const int nl = t >> 3, k4 = (t & 7) * 4;
    unsigned short o[4];
#pragma unroll
    for (int i = 0; i < 4; ++i) o[i] = f2bf(tl[k4 + i][nl]);
    *reinterpret_cast<ushort4*>(&dst[(size_t)(tx * 32 + nl) * K + ty * 32 + k4]) =
        *reinterpret_cast<const ushort4*>(o);
  }
}

// ---------------------------------------------------------------------------
// bf16 MFMA GEMM: C = act(A @ BT^T + bias).  A [M][KDIM] bf16, BT [N][KDIM]
// bf16.  128x128 tile, BK=32, 4 waves, mfma_f32_16x16x32_bf16,
// global_load_lds(16B) with XOR swizzle (chunk ^= (row>>1)&3).
// ACT: 0 relu, 1 tanh.  OBF16: bf16 output else fp32.  ldc in elements.
// ---------------------------------------------------------------------------
template <int ACT, int OBF16, int KDIM>
__global__ __launch_bounds__(256) void gemm_mfma(
    const unsigned short* __restrict__ A, const unsigned short* __restrict__ BT,
    const float* __restrict__ bias, void* __restrict__ Cv, int ldc) {
  __shared__ __align__(16) unsigned short As[128 * 32];
  __shared__ __align__(16) unsigned short Bs[128 * 32];

  const int t = threadIdx.x;
  const int lane = t & 63;
  const int w = t >> 6;
  const int bm = blockIdx.x * 128;
  const int bn = blockIdx.y * 128;

  const int r0 = w * 32 + (lane >> 2);
  const int r1 = r0 + 16;
  const int c0 = (lane & 3) ^ ((r0 >> 1) & 3);
  const int c1 = (lane & 3) ^ ((r1 >> 1) & 3);

  const unsigned short* gA0 = A + (size_t)(bm + r0) * KDIM + c0 * 8;
  const unsigned short* gA1 = A + (size_t)(bm + r1) * KDIM + c1 * 8;
  const unsigned short* gB0 = BT + (size_t)(bn + r0) * KDIM + c0 * 8;
  const unsigned short* gB1 = BT + (size_t)(bn + r1) * KDIM + c1 * 8;

  unsigned short* lA0 = &As[(w * 2 + 0) * 512];
  unsigned short* lA1 = &As[(w * 2 + 1) * 512];
  unsigned short* lB0 = &Bs[(w * 2 + 0) * 512];
  unsigned short* lB1 = &Bs[(w * 2 + 1) * 512];

  const int wm = (w >> 1) * 64;
  const int wn = (w & 1) * 64;
  const int lr = lane & 15;
  const int lc = lane >> 4;
  int aoff[4], boff[4];
#pragma unroll
  for (int i = 0; i < 4; ++i) {
    const int row = wm + i * 16 + lr;
    aoff[i] = row * 32 + (lc ^ ((row >> 1) & 3)) * 8;
    const int col = wn + i * 16 + lr;
    boff[i] = col * 32 + (lc ^ ((col >> 1) & 3)) * 8;
  }

  f32x4 acc[4][4];
  const f32x4 z = {0.f, 0.f, 0.f, 0.f};
#pragma unroll
  for (int i = 0; i < 4; ++i)
#pragma unroll
    for (int j = 0; j < 4; ++j) acc[i][j] = z;

#pragma unroll 1
  for (int kt = 0; kt < KDIM / 32; ++kt) {
    GLL16(gA0, lA0);
    GLL16(gA1, lA1);
    GLL16(gB0, lB0);
    GLL16(gB1, lB1);
    __syncthreads();

    short8 a[4], b[4];
#pragma unroll
    for (int i = 0; i < 4; ++i) a[i] = *reinterpret_cast<const short8*>(&As[aoff[i]]);
#pragma unroll
    for (int j = 0; j < 4; ++j) b[j] = *reinterpret_cast<const short8*>(&Bs[boff[j]]);

#pragma unroll
    for (int i = 0; i < 4; ++i)
#pragma unroll
      for (int j = 0; j < 4; ++j)
        acc[i][j] =
            __builtin_amdgcn_mfma_f32_16x16x32_bf16(a[i], b[j], acc[i][j], 0, 0, 0);

    __syncthreads();
    gA0 += 32; gA1 += 32; gB0 += 32; gB1 += 32;
  }

  // epilogue: C/D col = lane&15, row = (lane>>4)*4 + reg
  const int base_row = bm + wm + (lc << 2);
  const int base_col = bn + wn + lr;
#pragma unroll
  for (int i = 0; i < 4; ++i) {
#pragma unroll
    for (int j = 0; j < 4; ++j) {
      const int n = base_col + j * 16;
      const float bv = bias[n];
#pragma unroll
      for (int r = 0; r < 4; ++r) {
        const int m = base_row + i * 16 + r;
        float v = acc[i][j][r] + bv;
        v = (ACT == 0) ? fmaxf(v, 0.0f) : fast_tanh(v);
        if (OBF16)
          ((unsigned short*)Cv)[(size_t)m * ldc + n] = f2bf(v);
        else
          ((float*)Cv)[(size_t)m * ldc + n] = v;
      }
    }
  }
}

// ---------------------------------------------------------------------------
// Fused frequency MLP: fl = tanh(relu(msg@fW1+fb1)@fW2+fb2), fp32.
// 256 blocks x 16 rows.
// ---------------------------------------------------------------------------
__global__ __launch_bounds__(256) void freq_mlp(
    const float* __restrict__ msg, const float* __restrict__ fW1,
    const float* __restrict__ fb1, const float* __restrict__ fW2,
    const float* __restrict__ fb2, float* __restrict__ fl) {
  const int row0 = blockIdx.x * 16;
  const int t = threadIdx.x;

  __shared__ float ms[16 * 64];
  __shared__ float f1[16][128];

  *reinterpret_cast<float4*>(&ms[t * 4]) =
      *reinterpret_cast<const float4*>(&msg[(size_t)row0 * 64 + t * 4]);
  __syncthreads();

  {
    const int n = t & 127;
    const int rb = (t >> 7) * 8;
    float acc[8] = {};
    for (int k = 0; k < 64; ++k) {
      const float wv = fW1[k * 128 + n];
#pragma unroll
      for (int r = 0; r < 8; ++r) acc[r] += ms[(rb + r) * 64 + k] * wv;
    }
    const float bv = fb1[n];
#pragma unroll
    for (int r = 0; r < 8; ++r) f1[rb + r][n] = fmaxf(acc[r] + bv, 0.0f);
  }
  __syncthreads();

  {
    float acc[16] = {};
    for (int k = 0; k < 128; ++k) {
      const float wv = fW2[k * 256 + t];
#pragma unroll
      for (int r = 0; r < 16; ++r) acc[r] += f1[r][k] * wv;
    }
    const float bv = fb2[t];
#pragma unroll
    for (int r = 0; r < 16; ++r)
      fl[(size_t)(row0 + r) * 256 + t] = fast_tanh(acc[r] + bv);
  }
}

// ---------------------------------------------------------------------------
// Finalize: one block per (batch, channel). Build channel in LDS, separable
// 5x5 Gaussian, write [64,64] fp32 into d_out.
// ---------------------------------------------------------------------------
__global__ __launch_bounds__(256) void finalize_kernel(
    const float* __restrict__ msg, const float* __restrict__ fl_in,
    const unsigned short* __restrict__ spatial, float* __restrict__ out) {
  const int b = blockIdx.x;
  const int c = blockIdx.y;
  const int t = threadIdx.x;

  __shared__ float chan[4096];
  __shared__ float tmp[4096];
  __shared__ float fl[256];
  __shared__ float msgs[64];
  __shared__ int lo_tab[64];
  __shared__ float w_tab[64];

  const float g0 = 0.054488684549644346f;
  const float g1 = 0.24420134200323332f;
  const float g2 = 0.4026199468907953f;
  const float g[5] = {g0, g1, g2, g1, g0};

  if (c != 0) {
    if (t < 64) {
      msgs[t] = msg[(size_t)b * 64 + t];
      const float pos = (float)t * (15.0f / 63.0f);
      int lo = (int)floorf(pos);
      if (lo > 15) lo = 15;
      lo_tab[t] = lo;
      w_tab[t] = pos - (float)lo;
    }
    fl[t] = fl_in[(size_t)b * 256 + t];
  }
  __syncthreads();

  if (c == 0) {
    const short8* sp = reinterpret_cast<const short8*>(spatial + (size_t)b * 4096);
    for (int v = t; v < 512; v += 256) {
      const short8 s = sp[v];
#pragma unroll
      for (int j = 0; j < 8; ++j) chan[v * 8 + j] = bf2f((unsigned short)s[j]);
    }
  } else if (c == 1) {
    for (int i = t; i < 4096; i += 256) {
      const int p = i >> 6, q = i & 63;
      const int lp = lo_tab[p], lq = lo_tab[q];
      const int hp = lp < 15 ? lp + 1 : 15;
      const int hq = lq < 15 ? lq + 1 : 15;
      const float wp = w_tab[p], wq = w_tab[q];
      const float v00 = fl[lp * 16 + lq], v01 = fl[lp * 16 + hq];
      const float v10 = fl[hp * 16 + lq], v11 = fl[hp * 16 + hq];
      chan[i] = (1.0f - wp) * ((1.0f - wq) * v00 + wq * v01) +
                wp * ((1.0f - wq) * v10 + wq * v11);
    }
  } else {
    for (int i = t; i < 4096; i += 256) {
      const int p = i >> 6, q = i & 63;
      chan[i] = msgs[((p >> 3) << 3) + (q >> 3)];
    }
  }
  __syncthreads();

  for (int i = t; i < 4096; i += 256) {
    const int p = i >> 6, q = i & 63;
    float s = 0.0f;
#pragma unroll
    for (int d = -2; d <= 2; ++d) {
      const int qq = q + d;
      if (qq >= 0 && qq < 64) s += g[d + 2] * chan[p * 64 + qq];
    }
    tmp[i] = s;
  }
  __syncthreads();

  float4* dst = reinterpret_cast<float4*>(out + (size_t)b * 12288 + (size_t)c * 4096);
  for (int i = t; i < 1024; i += 256) {
    const int p = i >> 4;
    const int q4 = (i & 15) * 4;
    float s0 = 0.f, s1 = 0.f, s2 = 0.f, s3 = 0.f;
#pragma unroll
    for (int d = -2; d <= 2; ++d) {
      const int pp = p + d;
      if (pp >= 0 && pp < 64) {
        const float gg = g[d + 2];
        const int base = pp * 64 + q4;
        s0 += gg * tmp[base + 0];
        s1 += gg * tmp[base + 1];
        s2 += gg * tmp[base + 2];
        s3 += gg * tmp[base + 3];
      }
    }
    float4 v;
    v.x = s0; v.y = s1; v.z = s2; v.w = s3;
    dst[i] = v;
  }
}

// ---------------------------------------------------------------------------
extern "C" void kernel_launch(void* const* d_in, const int* in_sizes, int n_in,
                              void* d_out, int out_size, void* d_ws,
                              size_t ws_size, hipStream_t stream) {
  const float* msg = (const float*)d_in[0];
  const float* sW1 = (const float*)d_in[1];
  const float* sb1 = (const float*)d_in[2];
  const float* sW2 = (const float*)d_in[3];
  const float* sb2 = (const float*)d_in[4];
  const float* sW3 = (const float*)d_in[5];
  const float* sb3 = (const float*)d_in[6];
  const float* fW1 = (const float*)d_in[7];
  const float* fb1 = (const float*)d_in[8];
  const float* fW2 = (const float*)d_in[9];
  const float* fb2 = (const float*)d_in[10];

  float* out = (float*)d_out;
  char* wsb = (char*)d_ws;

  unsigned short* msgb = (unsigned short*)(wsb);                  // 512 KB
  unsigned short* w1T  = (unsigned short*)(wsb + (1 << 19));      // 32 KB
  unsigned short* w2T  = (unsigned short*)(wsb + (1 << 20));      // 256 KB
  unsigned short* w3T  = (unsigned short*)(wsb + (2 << 20));      // 4 MB
  unsigned short* h1   = (unsigned short*)(wsb + (8 << 20));      // 2 MB
  unsigned short* h2   = (unsigned short*)(wsb + (12 << 20));     // 4 MB
  unsigned short* spat = (unsigned short*)(wsb + (16 << 20));     // 32 MB
  float* fl            = (float*)(wsb + (48 << 20));              // 4 MB

  const dim3 blk(256);

  prep_kernel<<<dim3(2320), blk, 0, stream>>>(sW1, sW2, sW3, msg, w1T, w2T, w3T, msgb);

  // spatial MLP (bf16 MFMA chain)
  gemm_mfma<0, 1, 64><<<dim3(32, 2), blk, 0, stream>>>(msgb, w1T, sb1, h1, 256);
  gemm_mfma<0, 1, 256><<<dim3(32, 4), blk, 0, stream>>>(h1, w2T, sb2, h2, 512);
  gemm_mfma<1, 1, 512><<<dim3(32, 32), blk, 0, stream>>>(h2, w3T, sb3, spat, 4096);

  // frequency MLP (fused, fp32)
  freq_mlp<<<dim3(256), blk, 0, stream>>>(msg, fW1, fb1, fW2, fb2, fl);

  // upsample + block pattern + depthwise Gaussian
  finalize_kernel<<<dim3(BATCH, 3), blk, 0, stream>>>(msg, fl, spat, out);
}

// Round 5
// 340.984 us; speedup vs baseline: 1.6432x; 1.0125x over previous
//
#include <hip/hip_runtime.h>
#include <math.h>

#define BATCH 4096

typedef __attribute__((ext_vector_type(8))) short short8;
typedef __attribute__((ext_vector_type(4))) float f32x4;

__device__ __forceinline__ unsigned short f2bf(float f) {
  unsigned int u = __float_as_uint(f);
  u += 0x7FFF + ((u >> 16) & 1);  // RNE
  return (unsigned short)(u >> 16);
}

__device__ __forceinline__ float bf2f(unsigned short s) {
  return __uint_as_float(((unsigned int)s) << 16);
}

__device__ __forceinline__ float fast_tanh(float x) {
  const float e = __expf(2.0f * x);
  const float r = __builtin_amdgcn_rcpf(e + 1.0f);
  return fmaf(-2.0f, r, 1.0f);
}

#define GLL16(g, l)                                                    \
  __builtin_amdgcn_global_load_lds(                                    \
      (const __attribute__((address_space(1))) unsigned int*)(g),      \
      (__attribute__((address_space(3))) unsigned int*)(l), 16, 0, 0)

// ---------------------------------------------------------------------------
// prep: transpose+convert sW1/sW2/sW3 (fp32 [K][N]) -> bf16 [N][K], and
// convert msg -> bf16.
// ---------------------------------------------------------------------------
__global__ __launch_bounds__(256) void prep_kernel(
    const float* __restrict__ sW1, const float* __restrict__ sW2,
    const float* __restrict__ sW3, const float* __restrict__ msg,
    unsigned short* __restrict__ w1T, unsigned short* __restrict__ w2T,
    unsigned short* __restrict__ w3T, unsigned short* __restrict__ msgb) {
  const int b = blockIdx.x;
  const int t = threadIdx.x;

  if (b >= 2192) {  // msg convert: 128 blocks x 2048 floats
    const int i0 = (b - 2192) * 2048 + t * 8;
    const float4 v0 = *reinterpret_cast<const float4*>(&msg[i0]);
    const float4 v1 = *reinterpret_cast<const float4*>(&msg[i0 + 4]);
    short8 o;
    o[0] = (short)f2bf(v0.x); o[1] = (short)f2bf(v0.y);
    o[2] = (short)f2bf(v0.z); o[3] = (short)f2bf(v0.w);
    o[4] = (short)f2bf(v1.x); o[5] = (short)f2bf(v1.y);
    o[6] = (short)f2bf(v1.z); o[7] = (short)f2bf(v1.w);
    *reinterpret_cast<short8*>(&msgb[i0]) = o;
    return;
  }

  const float* src;
  unsigned short* dst;
  int K, N, lgtN, tile;
  if (b < 16) {
    src = sW1; dst = w1T; K = 64; N = 256; lgtN = 3; tile = b;
  } else if (b < 144) {
    src = sW2; dst = w2T; K = 256; N = 512; lgtN = 4; tile = b - 16;
  } else {
    src = sW3; dst = w3T; K = 512; N = 4096; lgtN = 7; tile = b - 144;
  }
  const int ty = tile >> lgtN;
  const int tx = tile & ((1 << lgtN) - 1);

  __shared__ float tl[32][33];
  {
    const int r = t >> 3, c4 = (t & 7) * 4;
    const float4 v =
        *reinterpret_cast<const float4*>(&src[(size_t)(ty * 32 + r) * N + tx * 32 + c4]);
    tl[r][c4 + 0] = v.x; tl[r][c4 + 1] = v.y;
    tl[r][c4 + 2] = v.z; tl[r][c4 + 3] = v.w;
  }
  __syncthreads();
  {
    const int nl = t >> 3, k4 = (t & 7) * 4;
    unsigned short o[4];
#pragma unroll
    for (int i = 0; i < 4; ++i) o[i] = f2bf(tl[k4 + i][nl]);
    *reinterpret_cast<ushort4*>(&dst[(size_t)(tx * 32 + nl) * K + ty * 32 + k4]) =
        *reinterpret_cast<const ushort4*>(o);
  }
}

// ---------------------------------------------------------------------------
// bf16 MFMA GEMM: C = act(A @ BT^T + bias).  A [M][KDIM] bf16, BT [N][KDIM].
// 128x128 tile, BK=64 (8 chunks/row, XOR swizzle c' = c ^ (row&7)),
// 4 waves, mfma_f32_16x16x32_bf16, global_load_lds(16B) staging with
// pre-swizzled global source (rule #21). XCD-aware block swizzle.
// ACT: 0 relu, 1 tanh. OBF16: bf16 out else fp32. NWG = total blocks.
// ---------------------------------------------------------------------------
template <int ACT, int OBF16, int KDIM, int NWG>
__global__ __launch_bounds__(256) void gemm_mfma(
    const unsigned short* __restrict__ A, const unsigned short* __restrict__ BT,
    const float* __restrict__ bias, void* __restrict__ Cv, int ldc) {
  __shared__ __align__(16) unsigned short As[128 * 64];
  __shared__ __align__(16) unsigned short Bs[128 * 64];

  const int t = threadIdx.x;
  const int lane = t & 63;
  const int w = t >> 6;

  // XCD-aware swizzle (nwg % 8 == 0 for all instantiations)
  const int orig = blockIdx.y * 32 + blockIdx.x;
  const int swz = (orig & 7) * (NWG >> 3) + (orig >> 3);
  const int bm = (swz & 31) * 128;          // gridDim.x == 32 always
  const int bn = (swz >> 5) * 128;

  // --- staging geometry: per matrix, 16 calls of 1KB; wave w does calls
  // q=0..3, covering rows R0 = (w*4+q)*8 .. +7.  Lane l -> row R0+(l>>3),
  // dest chunk c' = l&7, source chunk c = (l&7)^(l>>3)  (R0 % 8 == 0).
  const int lrow = lane >> 3;                 // 0..7
  const int lchunk = (lane & 7) ^ lrow;       // pre-swizzled source chunk
  const unsigned short* gA[4];
  const unsigned short* gB[4];
  unsigned short* lA[4];
  unsigned short* lB[4];
#pragma unroll
  for (int q = 0; q < 4; ++q) {
    const int R0 = (w * 4 + q) * 8;
    gA[q] = A + (size_t)(bm + R0 + lrow) * KDIM + lchunk * 8;
    gB[q] = BT + (size_t)(bn + R0 + lrow) * KDIM + lchunk * 8;
    lA[q] = &As[(w * 4 + q) * 512];
    lB[q] = &Bs[(w * 4 + q) * 512];
  }

  // --- fragment read offsets (short units): window kk in {0,1}
  const int wm = (w >> 1) * 64;
  const int wn = (w & 1) * 64;
  const int lr = lane & 15;
  const int lc = lane >> 4;
  int aoff[2][4], boff[2][4];
#pragma unroll
  for (int kk = 0; kk < 2; ++kk) {
#pragma unroll
    for (int i = 0; i < 4; ++i) {
      const int arow = wm + i * 16 + lr;
      aoff[kk][i] = arow * 64 + ((kk * 4 + lc) ^ (arow & 7)) * 8;
      const int brow = wn + i * 16 + lr;
      boff[kk][i] = brow * 64 + ((kk * 4 + lc) ^ (brow & 7)) * 8;
    }
  }

  f32x4 acc[4][4];
  const f32x4 z = {0.f, 0.f, 0.f, 0.f};
#pragma unroll
  for (int i = 0; i < 4; ++i)
#pragma unroll
    for (int j = 0; j < 4; ++j) acc[i][j] = z;

#pragma unroll 1
  for (int kt = 0; kt < KDIM / 64; ++kt) {
#pragma unroll
    for (int q = 0; q < 4; ++q) GLL16(gA[q], lA[q]);
#pragma unroll
    for (int q = 0; q < 4; ++q) GLL16(gB[q], lB[q]);
    __syncthreads();  // compiler drains vmcnt+lgkmcnt before barrier

#pragma unroll
    for (int kk = 0; kk < 2; ++kk) {
      short8 a[4], b[4];
#pragma unroll
      for (int i = 0; i < 4; ++i)
        a[i] = *reinterpret_cast<const short8*>(&As[aoff[kk][i]]);
#pragma unroll
      for (int j = 0; j < 4; ++j)
        b[j] = *reinterpret_cast<const short8*>(&Bs[boff[kk][j]]);
#pragma unroll
      for (int i = 0; i < 4; ++i)
#pragma unroll
        for (int j = 0; j < 4; ++j)
          acc[i][j] =
              __builtin_amdgcn_mfma_f32_16x16x32_bf16(a[i], b[j], acc[i][j], 0, 0, 0);
    }

    __syncthreads();
#pragma unroll
    for (int q = 0; q < 4; ++q) { gA[q] += 64; gB[q] += 64; }
  }

  // epilogue: C/D col = lane&15, row = (lane>>4)*4 + reg
  const int base_row = bm + wm + (lc << 2);
  const int base_col = bn + wn + lr;
#pragma unroll
  for (int i = 0; i < 4; ++i) {
#pragma unroll
    for (int j = 0; j < 4; ++j) {
      const int n = base_col + j * 16;
      const float bv = bias[n];
#pragma unroll
      for (int r = 0; r < 4; ++r) {
        const int m = base_row + i * 16 + r;
        float v = acc[i][j][r] + bv;
        v = (ACT == 0) ? fmaxf(v, 0.0f) : fast_tanh(v);
        if (OBF16)
          ((unsigned short*)Cv)[(size_t)m * ldc + n] = f2bf(v);
        else
          ((float*)Cv)[(size_t)m * ldc + n] = v;
      }
    }
  }
}

// ---------------------------------------------------------------------------
// Fused frequency MLP: fl = tanh(relu(msg@fW1+fb1)@fW2+fb2), fp32.
// ---------------------------------------------------------------------------
__global__ __launch_bounds__(256) void freq_mlp(
    const float* __restrict__ msg, const float* __restrict__ fW1,
    const float* __restrict__ fb1, const float* __restrict__ fW2,
    const float* __restrict__ fb2, float* __restrict__ fl) {
  const int row0 = blockIdx.x * 16;
  const int t = threadIdx.x;

  __shared__ float ms[16 * 64];
  __shared__ float f1[16][128];

  *reinterpret_cast<float4*>(&ms[t * 4]) =
      *reinterpret_cast<const float4*>(&msg[(size_t)row0 * 64 + t * 4]);
  __syncthreads();

  {
    const int n = t & 127;
    const int rb = (t >> 7) * 8;
    float acc[8] = {};
    for (int k = 0; k < 64; ++k) {
      const float wv = fW1[k * 128 + n];
#pragma unroll
      for (int r = 0; r < 8; ++r) acc[r] += ms[(rb + r) * 64 + k] * wv;
    }
    const float bv = fb1[n];
#pragma unroll
    for (int r = 0; r < 8; ++r) f1[rb + r][n] = fmaxf(acc[r] + bv, 0.0f);
  }
  __syncthreads();

  {
    float acc[16] = {};
    for (int k = 0; k < 128; ++k) {
      const float wv = fW2[k * 256 + t];
#pragma unroll
      for (int r = 0; r < 16; ++r) acc[r] += f1[r][k] * wv;
    }
    const float bv = fb2[t];
#pragma unroll
    for (int r = 0; r < 16; ++r)
      fl[(size_t)(row0 + r) * 256 + t] = fast_tanh(acc[r] + bv);
  }
}

// ---------------------------------------------------------------------------
// Finalize: one block per (batch, channel). Build channel in LDS, separable
// 5x5 Gaussian, write [64,64] fp32 into d_out.
// ---------------------------------------------------------------------------
__global__ __launch_bounds__(256) void finalize_kernel(
    const float* __restrict__ msg, const float* __restrict__ fl_in,
    const unsigned short* __restrict__ spatial, float* __restrict__ out) {
  const int b = blockIdx.x;
  const int c = blockIdx.y;
  const int t = threadIdx.x;

  __shared__ float chan[4096];
  __shared__ float tmp[4096];
  __shared__ float fl[256];
  __shared__ float msgs[64];
  __shared__ int lo_tab[64];
  __shared__ float w_tab[64];

  const float g0 = 0.054488684549644346f;
  const float g1 = 0.24420134200323332f;
  const float g2 = 0.4026199468907953f;
  const float g[5] = {g0, g1, g2, g1, g0};

  if (c != 0) {
    if (t < 64) {
      msgs[t] = msg[(size_t)b * 64 + t];
      const float pos = (float)t * (15.0f / 63.0f);
      int lo = (int)floorf(pos);
      if (lo > 15) lo = 15;
      lo_tab[t] = lo;
      w_tab[t] = pos - (float)lo;
    }
    fl[t] = fl_in[(size_t)b * 256 + t];
  }
  __syncthreads();

  if (c == 0) {
    const short8* sp = reinterpret_cast<const short8*>(spatial + (size_t)b * 4096);
    for (int v = t; v < 512; v += 256) {
      const short8 s = sp[v];
#pragma unroll
      for (int j = 0; j < 8; ++j) chan[v * 8 + j] = bf2f((unsigned short)s[j]);
    }
  } else if (c == 1) {
    for (int i = t; i < 4096; i += 256) {
      const int p = i >> 6, q = i & 63;
      const int lp = lo_tab[p], lq = lo_tab[q];
      const int hp = lp < 15 ? lp + 1 : 15;
      const int hq = lq < 15 ? lq + 1 : 15;
      const float wp = w_tab[p], wq = w_tab[q];
      const float v00 = fl[lp * 16 + lq], v01 = fl[lp * 16 + hq];
      const float v10 = fl[hp * 16 + lq], v11 = fl[hp * 16 + hq];
      chan[i] = (1.0f - wp) * ((1.0f - wq) * v00 + wq * v01) +
                wp * ((1.0f - wq) * v10 + wq * v11);
    }
  } else {
    for (int i = t; i < 4096; i += 256) {
      const int p = i >> 6, q = i & 63;
      chan[i] = msgs[((p >> 3) << 3) + (q >> 3)];
    }
  }
  __syncthreads();

  for (int i = t; i < 4096; i += 256) {
    const int p = i >> 6, q = i & 63;
    float s = 0.0f;
#pragma unroll
    for (int d = -2; d <= 2; ++d) {
      const int qq = q + d;
      if (qq >= 0 && qq < 64) s += g[d + 2] * chan[p * 64 + qq];
    }
    tmp[i] = s;
  }
  __syncthreads();

  float4* dst = reinterpret_cast<float4*>(out + (size_t)b * 12288 + (size_t)c * 4096);
  for (int i = t; i < 1024; i += 256) {
    const int p = i >> 4;
    const int q4 = (i & 15) * 4;
    float s0 = 0.f, s1 = 0.f, s2 = 0.f, s3 = 0.f;
#pragma unroll
    for (int d = -2; d <= 2; ++d) {
      const int pp = p + d;
      if (pp >= 0 && pp < 64) {
        const float gg = g[d + 2];
        const int base = pp * 64 + q4;
        s0 += gg * tmp[base + 0];
        s1 += gg * tmp[base + 1];
        s2 += gg * tmp[base + 2];
        s3 += gg * tmp[base + 3];
      }
    }
    float4 v;
    v.x = s0; v.y = s1; v.z = s2; v.w = s3;
    dst[i] = v;
  }
}

// ---------------------------------------------------------------------------
extern "C" void kernel_launch(void* const* d_in, const int* in_sizes, int n_in,
                              void* d_out, int out_size, void* d_ws,
                              size_t ws_size, hipStream_t stream) {
  const float* msg = (const float*)d_in[0];
  const float* sW1 = (const float*)d_in[1];
  const float* sb1 = (const float*)d_in[2];
  const float* sW2 = (const float*)d_in[3];
  const float* sb2 = (const float*)d_in[4];
  const float* sW3 = (const float*)d_in[5];
  const float* sb3 = (const float*)d_in[6];
  const float* fW1 = (const float*)d_in[7];
  const float* fb1 = (const float*)d_in[8];
  const float* fW2 = (const float*)d_in[9];
  const float* fb2 = (const float*)d_in[10];

  float* out = (float*)d_out;
  char* wsb = (char*)d_ws;

  unsigned short* msgb = (unsigned short*)(wsb);                  // 512 KB
  unsigned short* w1T  = (unsigned short*)(wsb + (1 << 19));      // 32 KB
  unsigned short* w2T  = (unsigned short*)(wsb + (1 << 20));      // 256 KB
  unsigned short* w3T  = (unsigned short*)(wsb + (2 << 20));      // 4 MB
  unsigned short* h1   = (unsigned short*)(wsb + (8 << 20));      // 2 MB
  unsigned short* h2   = (unsigned short*)(wsb + (12 << 20));     // 4 MB
  unsigned short* spat = (unsigned short*)(wsb + (16 << 20));     // 32 MB
  float* fl            = (float*)(wsb + (48 << 20));              // 4 MB

  const dim3 blk(256);

  prep_kernel<<<dim3(2320), blk, 0, stream>>>(sW1, sW2, sW3, msg, w1T, w2T, w3T, msgb);

  // spatial MLP (bf16 MFMA chain)
  gemm_mfma<0, 1, 64, 64><<<dim3(32, 2), blk, 0, stream>>>(msgb, w1T, sb1, h1, 256);
  gemm_mfma<0, 1, 256, 128><<<dim3(32, 4), blk, 0, stream>>>(h1, w2T, sb2, h2, 512);
  gemm_mfma<1, 1, 512, 1024><<<dim3(32, 32), blk, 0, stream>>>(h2, w3T, sb3, spat, 4096);

  // frequency MLP (fused, fp32)
  freq_mlp<<<dim3(256), blk, 0, stream>>>(msg, fW1, fb1, fW2, fb2, fl);

  // upsample + block pattern + depthwise Gaussian
  finalize_kernel<<<dim3(BATCH, 3), blk, 0, stream>>>(msg, fl, spat, out);
}

// Round 7
// 337.946 us; speedup vs baseline: 1.6579x; 1.0090x over previous
//
#include <hip/hip_runtime.h>
#include <math.h>

#define BATCH 4096

typedef __attribute__((ext_vector_type(8))) short short8;
typedef __attribute__((ext_vector_type(4))) float f32x4;

__device__ __forceinline__ unsigned short f2bf(float f) {
  unsigned int u = __float_as_uint(f);
  u += 0x7FFF + ((u >> 16) & 1);  // RNE
  return (unsigned short)(u >> 16);
}

__device__ __forceinline__ float bf2f(unsigned short s) {
  return __uint_as_float(((unsigned int)s) << 16);
}

__device__ __forceinline__ float fast_tanh(float x) {
  const float e = __expf(2.0f * x);
  const float r = __builtin_amdgcn_rcpf(e + 1.0f);
  return fmaf(-2.0f, r, 1.0f);
}

#define GLL16(g, l)                                                    \
  __builtin_amdgcn_global_load_lds(                                    \
      (const __attribute__((address_space(1))) unsigned int*)(g),      \
      (__attribute__((address_space(3))) unsigned int*)(l), 16, 0, 0)

// ---------------------------------------------------------------------------
// setup: freq MLP (blocks 0..255) + weight transpose/convert + msg convert
// (blocks 256..2575).
// ---------------------------------------------------------------------------
__global__ __launch_bounds__(256) void setup_kernel(
    const float* __restrict__ sW1, const float* __restrict__ sW2,
    const float* __restrict__ sW3, const float* __restrict__ msg,
    const float* __restrict__ fW1, const float* __restrict__ fb1,
    const float* __restrict__ fW2, const float* __restrict__ fb2,
    unsigned short* __restrict__ w1T, unsigned short* __restrict__ w2T,
    unsigned short* __restrict__ w3T, unsigned short* __restrict__ msgb,
    float* __restrict__ fl) {
  const int blk = blockIdx.x;
  const int t = threadIdx.x;

  __shared__ float ms[16 * 64];
  __shared__ float f1[16][128];
  __shared__ float tl[32][33];

  if (blk < 256) {  // ---- fused frequency MLP: 16 rows per block
    const int row0 = blk * 16;
    *reinterpret_cast<float4*>(&ms[t * 4]) =
        *reinterpret_cast<const float4*>(&msg[(size_t)row0 * 64 + t * 4]);
    __syncthreads();
    {
      const int n = t & 127;
      const int rb = (t >> 7) * 8;
      float acc[8] = {};
      for (int k = 0; k < 64; ++k) {
        const float wv = fW1[k * 128 + n];
#pragma unroll
        for (int r = 0; r < 8; ++r) acc[r] += ms[(rb + r) * 64 + k] * wv;
      }
      const float bv = fb1[n];
#pragma unroll
      for (int r = 0; r < 8; ++r) f1[rb + r][n] = fmaxf(acc[r] + bv, 0.0f);
    }
    __syncthreads();
    {
      float acc[16] = {};
      for (int k = 0; k < 128; ++k) {
        const float wv = fW2[k * 256 + t];
#pragma unroll
        for (int r = 0; r < 16; ++r) acc[r] += f1[r][k] * wv;
      }
      const float bv = fb2[t];
#pragma unroll
      for (int r = 0; r < 16; ++r)
        fl[(size_t)(row0 + r) * 256 + t] = fast_tanh(acc[r] + bv);
    }
    return;
  }

  const int b = blk - 256;
  if (b >= 2192) {  // msg convert: 128 blocks x 2048 floats
    const int i0 = (b - 2192) * 2048 + t * 8;
    const float4 v0 = *reinterpret_cast<const float4*>(&msg[i0]);
    const float4 v1 = *reinterpret_cast<const float4*>(&msg[i0 + 4]);
    short8 o;
    o[0] = (short)f2bf(v0.x); o[1] = (short)f2bf(v0.y);
    o[2] = (short)f2bf(v0.z); o[3] = (short)f2bf(v0.w);
    o[4] = (short)f2bf(v1.x); o[5] = (short)f2bf(v1.y);
    o[6] = (short)f2bf(v1.z); o[7] = (short)f2bf(v1.w);
    *reinterpret_cast<short8*>(&msgb[i0]) = o;
    return;
  }

  const float* src;
  unsigned short* dst;
  int K, N, lgtN, tile;
  if (b < 16) {
    src = sW1; dst = w1T; K = 64; N = 256; lgtN = 3; tile = b;
  } else if (b < 144) {
    src = sW2; dst = w2T; K = 256; N = 512; lgtN = 4; tile = b - 16;
  } else {
    src = sW3; dst = w3T; K = 512; N = 4096; lgtN = 7; tile = b - 144;
  }
  const int ty = tile >> lgtN;
  const int tx = tile & ((1 << lgtN) - 1);

  {
    const int r = t >> 3, c4 = (t & 7) * 4;
    const float4 v =
        *reinterpret_cast<const float4*>(&src[(size_t)(ty * 32 + r) * N + tx * 32 + c4]);
    tl[r][c4 + 0] = v.x; tl[r][c4 + 1] = v.y;
    tl[r][c4 + 2] = v.z; tl[r][c4 + 3] = v.w;
  }
  __syncthreads();
  {
    const int nl = t >> 3, k4 = (t & 7) * 4;
    unsigned short o[4];
#pragma unroll
    for (int i = 0; i < 4; ++i) o[i] = f2bf(tl[k4 + i][nl]);
    *reinterpret_cast<ushort4*>(&dst[(size_t)(tx * 32 + nl) * K + ty * 32 + k4]) =
        *reinterpret_cast<const ushort4*>(o);
  }
}

// ---------------------------------------------------------------------------
// bf16 MFMA GEMM: C = act(A @ BT^T + bias).  A [M][KDIM] bf16, BT [N][KDIM].
// 128x128 tile, BK=32, DOUBLE-BUFFERED 1-barrier-per-K-step pipeline:
// issue next tile's global_load_lds into buf^1 BEFORE computing buf, then a
// single __syncthreads (vmcnt(0)+barrier) per step — staging overlaps MFMA.
// XOR swizzle chunk c' = c ^ ((row>>1)&3); pre-swizzled global source.
// XCD-aware block swizzle. ACT: 0 relu, 1 tanh. OBF16: bf16 out else fp32.
// ---------------------------------------------------------------------------
template <int ACT, int OBF16, int KDIM, int NWG>
__global__ __launch_bounds__(256) void gemm_mfma(
    const unsigned short* __restrict__ A, const unsigned short* __restrict__ BT,
    const float* __restrict__ bias, void* __restrict__ Cv, int ldc) {
  __shared__ __align__(16) unsigned short As[2][128 * 32];
  __shared__ __align__(16) unsigned short Bs[2][128 * 32];

  const int t = threadIdx.x;
  const int lane = t & 63;
  const int w = t >> 6;

  // XCD-aware swizzle (NWG % 8 == 0 for all instantiations)
  const int orig = blockIdx.y * 32 + blockIdx.x;
  const int swz = (orig & 7) * (NWG >> 3) + (orig >> 3);
  const int bm = (swz & 31) * 128;  // gridDim.x == 32 always
  const int bn = (swz >> 5) * 128;

  // staging: wave w stages rows 32w..32w+31 of A and B (2 GLL each).
  // lane l -> row r = R0 + (l>>2), dest chunk l&3, src chunk (l&3)^((r>>1)&3)
  const int r0 = w * 32 + (lane >> 2);
  const int r1 = r0 + 16;
  const int c0 = (lane & 3) ^ ((r0 >> 1) & 3);
  const int c1 = (lane & 3) ^ ((r1 >> 1) & 3);

  const unsigned short* gA0 = A + (size_t)(bm + r0) * KDIM + c0 * 8;
  const unsigned short* gA1 = A + (size_t)(bm + r1) * KDIM + c1 * 8;
  const unsigned short* gB0 = BT + (size_t)(bn + r0) * KDIM + c0 * 8;
  const unsigned short* gB1 = BT + (size_t)(bn + r1) * KDIM + c1 * 8;

  const int lofs0 = (w * 2 + 0) * 512;
  const int lofs1 = (w * 2 + 1) * 512;

  // fragment read offsets (short units)
  const int wm = (w >> 1) * 64;
  const int wn = (w & 1) * 64;
  const int lr = lane & 15;
  const int lc = lane >> 4;
  int aoff[4], boff[4];
#pragma unroll
  for (int i = 0; i < 4; ++i) {
    const int arow = wm + i * 16 + lr;
    aoff[i] = arow * 32 + (lc ^ ((arow >> 1) & 3)) * 8;
    const int brow = wn + i * 16 + lr;
    boff[i] = brow * 32 + (lc ^ ((brow >> 1) & 3)) * 8;
  }

  f32x4 acc[4][4];
  const f32x4 z = {0.f, 0.f, 0.f, 0.f};
#pragma unroll
  for (int i = 0; i < 4; ++i)
#pragma unroll
    for (int j = 0; j < 4; ++j) acc[i][j] = z;

  constexpr int NT = KDIM / 32;

  // prologue: stage tile 0 into buffer 0
  GLL16(gA0, &As[0][lofs0]);
  GLL16(gA1, &As[0][lofs1]);
  GLL16(gB0, &Bs[0][lofs0]);
  GLL16(gB1, &Bs[0][lofs1]);
  gA0 += 32; gA1 += 32; gB0 += 32; gB1 += 32;
  __syncthreads();

  int cur = 0;
#pragma unroll 1
  for (int kt = 0; kt < NT; ++kt) {
    if (kt + 1 < NT) {  // issue next-tile loads early (overlap with compute)
      const int nxt = cur ^ 1;
      GLL16(gA0, &As[nxt][lofs0]);
      GLL16(gA1, &As[nxt][lofs1]);
      GLL16(gB0, &Bs[nxt][lofs0]);
      GLL16(gB1, &Bs[nxt][lofs1]);
      gA0 += 32; gA1 += 32; gB0 += 32; gB1 += 32;
    }

    short8 a[4], b[4];
#pragma unroll
    for (int i = 0; i < 4; ++i)
      a[i] = *reinterpret_cast<const short8*>(&As[cur][aoff[i]]);
#pragma unroll
    for (int j = 0; j < 4; ++j)
      b[j] = *reinterpret_cast<const short8*>(&Bs[cur][boff[j]]);

#pragma unroll
    for (int i = 0; i < 4; ++i)
#pragma unroll
      for (int j = 0; j < 4; ++j)
        acc[i][j] =
            __builtin_amdgcn_mfma_f32_16x16x32_bf16(a[i], b[j], acc[i][j], 0, 0, 0);

    __syncthreads();  // drains vmcnt (prefetch landed) + protects buffers
    cur ^= 1;
  }

  // epilogue: C/D col = lane&15, row = (lane>>4)*4 + reg
  const int base_row = bm + wm + (lc << 2);
  const int base_col = bn + wn + lr;
#pragma unroll
  for (int i = 0; i < 4; ++i) {
#pragma unroll
    for (int j = 0; j < 4; ++j) {
      const int n = base_col + j * 16;
      const float bv = bias[n];
#pragma unroll
      for (int r = 0; r < 4; ++r) {
        const int m = base_row + i * 16 + r;
        float v = acc[i][j][r] + bv;
        v = (ACT == 0) ? fmaxf(v, 0.0f) : fast_tanh(v);
        if (OBF16)
          ((unsigned short*)Cv)[(size_t)m * ldc + n] = f2bf(v);
        else
          ((float*)Cv)[(size_t)m * ldc + n] = v;
      }
    }
  }
}

// ---------------------------------------------------------------------------
// Finalize: one block per (batch, channel). Build channel in LDS, separable
// 5x5 Gaussian, write [64,64] fp32 into d_out.
// ---------------------------------------------------------------------------
__global__ __launch_bounds__(256) void finalize_kernel(
    const float* __restrict__ msg, const float* __restrict__ fl_in,
    const unsigned short* __restrict__ spatial, float* __restrict__ out) {
  const int b = blockIdx.x;
  const int c = blockIdx.y;
  const int t = threadIdx.x;

  __shared__ float chan[4096];
  __shared__ float tmp[4096];
  __shared__ float fl[256];
  __shared__ float msgs[64];
  __shared__ int lo_tab[64];
  __shared__ float w_tab[64];

  const float g0 = 0.054488684549644346f;
  const float g1 = 0.24420134200323332f;
  const float g2 = 0.4026199468907953f;
  const float g[5] = {g0, g1, g2, g1, g0};

  if (c != 0) {
    if (t < 64) {
      msgs[t] = msg[(size_t)b * 64 + t];
      const float pos = (float)t * (15.0f / 63.0f);
      int lo = (int)floorf(pos);
      if (lo > 15) lo = 15;
      lo_tab[t] = lo;
      w_tab[t] = pos - (float)lo;
    }
    fl[t] = fl_in[(size_t)b * 256 + t];
  }
  __syncthreads();

  if (c == 0) {
    const short8* sp = reinterpret_cast<const short8*>(spatial + (size_t)b * 4096);
    for (int v = t; v < 512; v += 256) {
      const short8 s = sp[v];
#pragma unroll
      for (int j = 0; j < 8; ++j) chan[v * 8 + j] = bf2f((unsigned short)s[j]);
    }
  } else if (c == 1) {
    for (int i = t; i < 4096; i += 256) {
      const int p = i >> 6, q = i & 63;
      const int lp = lo_tab[p], lq = lo_tab[q];
      const int hp = lp < 15 ? lp + 1 : 15;
      const int hq = lq < 15 ? lq + 1 : 15;
      const float wp = w_tab[p], wq = w_tab[q];
      const float v00 = fl[lp * 16 + lq], v01 = fl[lp * 16 + hq];
      const float v10 = fl[hp * 16 + lq], v11 = fl[hp * 16 + hq];
      chan[i] = (1.0f - wp) * ((1.0f - wq) * v00 + wq * v01) +
                wp * ((1.0f - wq) * v10 + wq * v11);
    }
  } else {
    for (int i = t; i < 4096; i += 256) {
      const int p = i >> 6, q = i & 63;
      chan[i] = msgs[((p >> 3) << 3) + (q >> 3)];
    }
  }
  __syncthreads();

  for (int i = t; i < 4096; i += 256) {
    const int p = i >> 6, q = i & 63;
    float s = 0.0f;
#pragma unroll
    for (int d = -2; d <= 2; ++d) {
      const int qq = q + d;
      if (qq >= 0 && qq < 64) s += g[d + 2] * chan[p * 64 + qq];
    }
    tmp[i] = s;
  }
  __syncthreads();

  float4* dst = reinterpret_cast<float4*>(out + (size_t)b * 12288 + (size_t)c * 4096);
  for (int i = t; i < 1024; i += 256) {
    const int p = i >> 4;
    const int q4 = (i & 15) * 4;
    float s0 = 0.f, s1 = 0.f, s2 = 0.f, s3 = 0.f;
#pragma unroll
    for (int d = -2; d <= 2; ++d) {
      const int pp = p + d;
      if (pp >= 0 && pp < 64) {
        const float gg = g[d + 2];
        const int base = pp * 64 + q4;
        s0 += gg * tmp[base + 0];
        s1 += gg * tmp[base + 1];
        s2 += gg * tmp[base + 2];
        s3 += gg * tmp[base + 3];
      }
    }
    float4 v;
    v.x = s0; v.y = s1; v.z = s2; v.w = s3;
    dst[i] = v;
  }
}

// ---------------------------------------------------------------------------
extern "C" void kernel_launch(void* const* d_in, const int* in_sizes, int n_in,
                              void* d_out, int out_size, void* d_ws,
                              size_t ws_size, hipStream_t stream) {
  const float* msg = (const float*)d_in[0];
  const float* sW1 = (const float*)d_in[1];
  const float* sb1 = (const float*)d_in[2];
  const float* sW2 = (const float*)d_in[3];
  const float* sb2 = (const float*)d_in[4];
  const float* sW3 = (const float*)d_in[5];
  const float* sb3 = (const float*)d_in[6];
  const float* fW1 = (const float*)d_in[7];
  const float* fb1 = (const float*)d_in[8];
  const float* fW2 = (const float*)d_in[9];
  const float* fb2 = (const float*)d_in[10];

  float* out = (float*)d_out;
  char* wsb = (char*)d_ws;

  unsigned short* msgb = (unsigned short*)(wsb);                  // 512 KB
  unsigned short* w1T  = (unsigned short*)(wsb + (1 << 19));      // 32 KB
  unsigned short* w2T  = (unsigned short*)(wsb + (1 << 20));      // 256 KB
  unsigned short* w3T  = (unsigned short*)(wsb + (2 << 20));      // 4 MB
  unsigned short* h1   = (unsigned short*)(wsb + (8 << 20));      // 2 MB
  unsigned short* h2   = (unsigned short*)(wsb + (12 << 20));     // 4 MB
  unsigned short* spat = (unsigned short*)(wsb + (16 << 20));     // 32 MB
  float* fl            = (float*)(wsb + (48 << 20));              // 4 MB

  const dim3 blk(256);

  // freq MLP + weight prep (independent of GEMM chain)
  setup_kernel<<<dim3(2576), blk, 0, stream>>>(sW1, sW2, sW3, msg, fW1, fb1,
                                               fW2, fb2, w1T, w2T, w3T, msgb, fl);

  // spatial MLP (bf16 MFMA chain, 2-phase pipelined)
  gemm_mfma<0, 1, 64, 64><<<dim3(32, 2), blk, 0, stream>>>(msgb, w1T, sb1, h1, 256);
  gemm_mfma<0, 1, 256, 128><<<dim3(32, 4), blk, 0, stream>>>(h1, w2T, sb2, h2, 512);
  gemm_mfma<1, 1, 512, 1024><<<dim3(32, 32), blk, 0, stream>>>(h2, w3T, sb3, spat, 4096);

  // upsample + block pattern + depthwise Gaussian
  finalize_kernel<<<dim3(BATCH, 3), blk, 0, stream>>>(msg, fl, spat, out);
}

// Round 8
// 308.372 us; speedup vs baseline: 1.8169x; 1.0959x over previous
//
#include <hip/hip_runtime.h>
#include <math.h>

#define BATCH 4096

typedef __attribute__((ext_vector_type(8))) short short8;
typedef __attribute__((ext_vector_type(4))) float f32x4;

__device__ __forceinline__ unsigned short f2bf(float f) {
  unsigned int u = __float_as_uint(f);
  u += 0x7FFF + ((u >> 16) & 1);  // RNE
  return (unsigned short)(u >> 16);
}

__device__ __forceinline__ float bf2f(unsigned short s) {
  return __uint_as_float(((unsigned int)s) << 16);
}

__device__ __forceinline__ float fast_tanh(float x) {
  const float e = __expf(2.0f * x);
  const float r = __builtin_amdgcn_rcpf(e + 1.0f);
  return fmaf(-2.0f, r, 1.0f);
}

#define GLL16(g, l)                                                    \
  __builtin_amdgcn_global_load_lds(                                    \
      (const __attribute__((address_space(1))) unsigned int*)(g),      \
      (__attribute__((address_space(3))) unsigned int*)(l), 16, 0, 0)

// ---------------------------------------------------------------------------
// setup: freq MLP (blocks 0..255) + weight transpose/convert + msg convert
// (blocks 256..2575).
// ---------------------------------------------------------------------------
__global__ __launch_bounds__(256) void setup_kernel(
    const float* __restrict__ sW1, const float* __restrict__ sW2,
    const float* __restrict__ sW3, const float* __restrict__ msg,
    const float* __restrict__ fW1, const float* __restrict__ fb1,
    const float* __restrict__ fW2, const float* __restrict__ fb2,
    unsigned short* __restrict__ w1T, unsigned short* __restrict__ w2T,
    unsigned short* __restrict__ w3T, unsigned short* __restrict__ msgb,
    float* __restrict__ fl) {
  const int blk = blockIdx.x;
  const int t = threadIdx.x;

  __shared__ float ms[16 * 64];
  __shared__ float f1[16][128];
  __shared__ float tl[32][33];

  if (blk < 256) {  // ---- fused frequency MLP: 16 rows per block
    const int row0 = blk * 16;
    *reinterpret_cast<float4*>(&ms[t * 4]) =
        *reinterpret_cast<const float4*>(&msg[(size_t)row0 * 64 + t * 4]);
    __syncthreads();
    {
      const int n = t & 127;
      const int rb = (t >> 7) * 8;
      float acc[8] = {};
      for (int k = 0; k < 64; ++k) {
        const float wv = fW1[k * 128 + n];
#pragma unroll
        for (int r = 0; r < 8; ++r) acc[r] += ms[(rb + r) * 64 + k] * wv;
      }
      const float bv = fb1[n];
#pragma unroll
      for (int r = 0; r < 8; ++r) f1[rb + r][n] = fmaxf(acc[r] + bv, 0.0f);
    }
    __syncthreads();
    {
      float acc[16] = {};
      for (int k = 0; k < 128; ++k) {
        const float wv = fW2[k * 256 + t];
#pragma unroll
        for (int r = 0; r < 16; ++r) acc[r] += f1[r][k] * wv;
      }
      const float bv = fb2[t];
#pragma unroll
      for (int r = 0; r < 16; ++r)
        fl[(size_t)(row0 + r) * 256 + t] = fast_tanh(acc[r] + bv);
    }
    return;
  }

  const int b = blk - 256;
  if (b >= 2192) {  // msg convert: 128 blocks x 2048 floats
    const int i0 = (b - 2192) * 2048 + t * 8;
    const float4 v0 = *reinterpret_cast<const float4*>(&msg[i0]);
    const float4 v1 = *reinterpret_cast<const float4*>(&msg[i0 + 4]);
    short8 o;
    o[0] = (short)f2bf(v0.x); o[1] = (short)f2bf(v0.y);
    o[2] = (short)f2bf(v0.z); o[3] = (short)f2bf(v0.w);
    o[4] = (short)f2bf(v1.x); o[5] = (short)f2bf(v1.y);
    o[6] = (short)f2bf(v1.z); o[7] = (short)f2bf(v1.w);
    *reinterpret_cast<short8*>(&msgb[i0]) = o;
    return;
  }

  const float* src;
  unsigned short* dst;
  int K, N, lgtN, tile;
  if (b < 16) {
    src = sW1; dst = w1T; K = 64; N = 256; lgtN = 3; tile = b;
  } else if (b < 144) {
    src = sW2; dst = w2T; K = 256; N = 512; lgtN = 4; tile = b - 16;
  } else {
    src = sW3; dst = w3T; K = 512; N = 4096; lgtN = 7; tile = b - 144;
  }
  const int ty = tile >> lgtN;
  const int tx = tile & ((1 << lgtN) - 1);

  {
    const int r = t >> 3, c4 = (t & 7) * 4;
    const float4 v =
        *reinterpret_cast<const float4*>(&src[(size_t)(ty * 32 + r) * N + tx * 32 + c4]);
    tl[r][c4 + 0] = v.x; tl[r][c4 + 1] = v.y;
    tl[r][c4 + 2] = v.z; tl[r][c4 + 3] = v.w;
  }
  __syncthreads();
  {
    const int nl = t >> 3, k4 = (t & 7) * 4;
    unsigned short o[4];
#pragma unroll
    for (int i = 0; i < 4; ++i) o[i] = f2bf(tl[k4 + i][nl]);
    *reinterpret_cast<ushort4*>(&dst[(size_t)(tx * 32 + nl) * K + ty * 32 + k4]) =
        *reinterpret_cast<const ushort4*>(o);
  }
}

// ---------------------------------------------------------------------------
// bf16 MFMA GEMM: C = act(A @ BT^T + bias).  A [M][KDIM] bf16, BT [N][KDIM].
// 128x128 tile, BK=32, double-buffered with COUNTED vmcnt + raw s_barrier
// (T4): per iter {stage next (4 loads/wave) -> s_waitcnt vmcnt(4) -> barrier
// -> ds_read+MFMA -> barrier}. Loads stay in flight across barriers; no
// vmcnt(0) drain in the main loop.
// XOR swizzle chunk c' = c ^ ((row>>1)&3); pre-swizzled global source.
// XCD-aware block swizzle. ACT: 0 relu, 1 tanh. OBF16: bf16 out else fp32.
// ---------------------------------------------------------------------------
template <int ACT, int OBF16, int KDIM, int NWG>
__global__ __launch_bounds__(256) void gemm_mfma(
    const unsigned short* __restrict__ A, const unsigned short* __restrict__ BT,
    const float* __restrict__ bias, void* __restrict__ Cv, int ldc) {
  __shared__ __align__(16) unsigned short As[2][128 * 32];
  __shared__ __align__(16) unsigned short Bs[2][128 * 32];

  const int t = threadIdx.x;
  const int lane = t & 63;
  const int w = t >> 6;

  // XCD-aware swizzle (NWG % 8 == 0 for all instantiations)
  const int orig = blockIdx.y * 32 + blockIdx.x;
  const int swz = (orig & 7) * (NWG >> 3) + (orig >> 3);
  const int bm = (swz & 31) * 128;  // gridDim.x == 32 always
  const int bn = (swz >> 5) * 128;

  // staging: wave w stages rows 32w..32w+31 of A and B (2 GLL each).
  const int r0 = w * 32 + (lane >> 2);
  const int r1 = r0 + 16;
  const int c0 = (lane & 3) ^ ((r0 >> 1) & 3);
  const int c1 = (lane & 3) ^ ((r1 >> 1) & 3);

  const unsigned short* gA0 = A + (size_t)(bm + r0) * KDIM + c0 * 8;
  const unsigned short* gA1 = A + (size_t)(bm + r1) * KDIM + c1 * 8;
  const unsigned short* gB0 = BT + (size_t)(bn + r0) * KDIM + c0 * 8;
  const unsigned short* gB1 = BT + (size_t)(bn + r1) * KDIM + c1 * 8;

  const int lofs0 = (w * 2 + 0) * 512;
  const int lofs1 = (w * 2 + 1) * 512;

  // fragment read offsets (short units)
  const int wm = (w >> 1) * 64;
  const int wn = (w & 1) * 64;
  const int lr = lane & 15;
  const int lc = lane >> 4;
  int aoff[4], boff[4];
#pragma unroll
  for (int i = 0; i < 4; ++i) {
    const int arow = wm + i * 16 + lr;
    aoff[i] = arow * 32 + (lc ^ ((arow >> 1) & 3)) * 8;
    const int brow = wn + i * 16 + lr;
    boff[i] = brow * 32 + (lc ^ ((brow >> 1) & 3)) * 8;
  }

  f32x4 acc[4][4];
  const f32x4 z = {0.f, 0.f, 0.f, 0.f};
#pragma unroll
  for (int i = 0; i < 4; ++i)
#pragma unroll
    for (int j = 0; j < 4; ++j) acc[i][j] = z;

  constexpr int NT = KDIM / 32;

  // prologue: stage tile 0 into buffer 0 (4 loads/wave in flight)
  GLL16(gA0, &As[0][lofs0]);
  GLL16(gA1, &As[0][lofs1]);
  GLL16(gB0, &Bs[0][lofs0]);
  GLL16(gB1, &Bs[0][lofs1]);
  gA0 += 32; gA1 += 32; gB0 += 32; gB1 += 32;

  int cur = 0;
#pragma unroll 1
  for (int kt = 0; kt < NT; ++kt) {
    if (kt + 1 < NT) {  // stage next tile; wait only for the PREVIOUS stage
      const int nxt = cur ^ 1;
      GLL16(gA0, &As[nxt][lofs0]);
      GLL16(gA1, &As[nxt][lofs1]);
      GLL16(gB0, &Bs[nxt][lofs0]);
      GLL16(gB1, &Bs[nxt][lofs1]);
      gA0 += 32; gA1 += 32; gB0 += 32; gB1 += 32;
      asm volatile("s_waitcnt vmcnt(4)" ::: "memory");
    } else {
      asm volatile("s_waitcnt vmcnt(0)" ::: "memory");
    }
    __builtin_amdgcn_sched_barrier(0);
    __builtin_amdgcn_s_barrier();  // buf cur complete & visible to all waves

    short8 a[4], b[4];
#pragma unroll
    for (int i = 0; i < 4; ++i)
      a[i] = *reinterpret_cast<const short8*>(&As[cur][aoff[i]]);
#pragma unroll
    for (int j = 0; j < 4; ++j)
      b[j] = *reinterpret_cast<const short8*>(&Bs[cur][boff[j]]);

#pragma unroll
    for (int i = 0; i < 4; ++i)
#pragma unroll
      for (int j = 0; j < 4; ++j)
        acc[i][j] =
            __builtin_amdgcn_mfma_f32_16x16x32_bf16(a[i], b[j], acc[i][j], 0, 0, 0);

    // all waves' ds_reads of buf cur are complete (lgkm dep before MFMA);
    // next iter's overwrite of cur is issued only after this barrier.
    __builtin_amdgcn_s_barrier();
    cur ^= 1;
  }

  // epilogue: C/D col = lane&15, row = (lane>>4)*4 + reg
  const int base_row = bm + wm + (lc << 2);
  const int base_col = bn + wn + lr;
#pragma unroll
  for (int i = 0; i < 4; ++i) {
#pragma unroll
    for (int j = 0; j < 4; ++j) {
      const int n = base_col + j * 16;
      const float bv = bias[n];
#pragma unroll
      for (int r = 0; r < 4; ++r) {
        const int m = base_row + i * 16 + r;
        float v = acc[i][j][r] + bv;
        v = (ACT == 0) ? fmaxf(v, 0.0f) : fast_tanh(v);
        if (OBF16)
          ((unsigned short*)Cv)[(size_t)m * ldc + n] = f2bf(v);
        else
          ((float*)Cv)[(size_t)m * ldc + n] = v;
      }
    }
  }
}

// ---------------------------------------------------------------------------
// Finalize: one block per (batch, channel). Build channel in LDS (float4),
// separable 5x5 Gaussian with float4 LDS reads, write [64,64] fp32.
// ---------------------------------------------------------------------------
__global__ __launch_bounds__(256) void finalize_kernel(
    const float* __restrict__ msg, const float* __restrict__ fl_in,
    const unsigned short* __restrict__ spatial, float* __restrict__ out) {
  const int b = blockIdx.x;
  const int c = blockIdx.y;
  const int t = threadIdx.x;

  __shared__ float chan[4096];
  __shared__ float tmp[4096];
  __shared__ float fl[256];
  __shared__ float msgs[64];
  __shared__ int lo_tab[64];
  __shared__ float w_tab[64];

  const float g0 = 0.054488684549644346f;
  const float g1 = 0.24420134200323332f;
  const float g2 = 0.4026199468907953f;
  const float g[5] = {g0, g1, g2, g1, g0};

  if (c != 0) {
    if (t < 64) {
      msgs[t] = msg[(size_t)b * 64 + t];
      const float pos = (float)t * (15.0f / 63.0f);
      int lo = (int)floorf(pos);
      if (lo > 15) lo = 15;
      lo_tab[t] = lo;
      w_tab[t] = pos - (float)lo;
    }
    fl[t] = fl_in[(size_t)b * 256 + t];
  }
  __syncthreads();

  if (c == 0) {
    const short8* sp = reinterpret_cast<const short8*>(spatial + (size_t)b * 4096);
    for (int v = t; v < 512; v += 256) {
      const short8 s = sp[v];
      float4 lo4, hi4;
      lo4.x = bf2f((unsigned short)s[0]); lo4.y = bf2f((unsigned short)s[1]);
      lo4.z = bf2f((unsigned short)s[2]); lo4.w = bf2f((unsigned short)s[3]);
      hi4.x = bf2f((unsigned short)s[4]); hi4.y = bf2f((unsigned short)s[5]);
      hi4.z = bf2f((unsigned short)s[6]); hi4.w = bf2f((unsigned short)s[7]);
      *reinterpret_cast<float4*>(&chan[v * 8]) = lo4;
      *reinterpret_cast<float4*>(&chan[v * 8 + 4]) = hi4;
    }
  } else if (c == 1) {
    for (int i = t; i < 4096; i += 256) {
      const int p = i >> 6, q = i & 63;
      const int lp = lo_tab[p], lq = lo_tab[q];
      const int hp = lp < 15 ? lp + 1 : 15;
      const int hq = lq < 15 ? lq + 1 : 15;
      const float wp = w_tab[p], wq = w_tab[q];
      const float v00 = fl[lp * 16 + lq], v01 = fl[lp * 16 + hq];
      const float v10 = fl[hp * 16 + lq], v11 = fl[hp * 16 + hq];
      chan[i] = (1.0f - wp) * ((1.0f - wq) * v00 + wq * v01) +
                wp * ((1.0f - wq) * v10 + wq * v11);
    }
  } else {
    for (int i = t; i < 1024; i += 256) {
      const int p = i >> 4, q4 = (i & 15) * 4;
      const float v = msgs[((p >> 3) << 3) + (q4 >> 3)];
      float4 sv; sv.x = v; sv.y = v; sv.z = v; sv.w = v;
      *reinterpret_cast<float4*>(&chan[p * 64 + q4]) = sv;
    }
  }
  __syncthreads();

  // horizontal pass: 4 outputs/thread-iter via 3 float4 LDS reads
  for (int i = t; i < 1024; i += 256) {
    const int p = i >> 4, q4 = (i & 15) * 4;
    const float* row = &chan[p * 64];
    const float4 C = *reinterpret_cast<const float4*>(&row[q4]);
    float4 L = {0.f, 0.f, 0.f, 0.f}, R = {0.f, 0.f, 0.f, 0.f};
    if (q4 > 0) L = *reinterpret_cast<const float4*>(&row[q4 - 4]);
    if (q4 < 60) R = *reinterpret_cast<const float4*>(&row[q4 + 4]);
    float4 o;
    o.x = g0 * L.z + g1 * L.w + g2 * C.x + g1 * C.y + g0 * C.z;
    o.y = g0 * L.w + g1 * C.x + g2 * C.y + g1 * C.z + g0 * C.w;
    o.z = g0 * C.x + g1 * C.y + g2 * C.z + g1 * C.w + g0 * R.x;
    o.w = g0 * C.y + g1 * C.z + g2 * C.w + g1 * R.x + g0 * R.y;
    *reinterpret_cast<float4*>(&tmp[p * 64 + q4]) = o;
  }
  __syncthreads();

  // vertical pass + store: 5 float4 LDS reads per 4 outputs
  float4* dst = reinterpret_cast<float4*>(out + (size_t)b * 12288 + (size_t)c * 4096);
  for (int i = t; i < 1024; i += 256) {
    const int p = i >> 4, q4 = (i & 15) * 4;
    float4 acc = {0.f, 0.f, 0.f, 0.f};
#pragma unroll
    for (int d = -2; d <= 2; ++d) {
      const int pp = p + d;
      if (pp >= 0 && pp < 64) {
        const float gg = g[d + 2];
        const float4 tv = *reinterpret_cast<const float4*>(&tmp[pp * 64 + q4]);
        acc.x += gg * tv.x; acc.y += gg * tv.y;
        acc.z += gg * tv.z; acc.w += gg * tv.w;
      }
    }
    dst[i] = acc;
  }
}

// ---------------------------------------------------------------------------
extern "C" void kernel_launch(void* const* d_in, const int* in_sizes, int n_in,
                              void* d_out, int out_size, void* d_ws,
                              size_t ws_size, hipStream_t stream) {
  const float* msg = (const float*)d_in[0];
  const float* sW1 = (const float*)d_in[1];
  const float* sb1 = (const float*)d_in[2];
  const float* sW2 = (const float*)d_in[3];
  const float* sb2 = (const float*)d_in[4];
  const float* sW3 = (const float*)d_in[5];
  const float* sb3 = (const float*)d_in[6];
  const float* fW1 = (const float*)d_in[7];
  const float* fb1 = (const float*)d_in[8];
  const float* fW2 = (const float*)d_in[9];
  const float* fb2 = (const float*)d_in[10];

  float* out = (float*)d_out;
  char* wsb = (char*)d_ws;

  unsigned short* msgb = (unsigned short*)(wsb);                  // 512 KB
  unsigned short* w1T  = (unsigned short*)(wsb + (1 << 19));      // 32 KB
  unsigned short* w2T  = (unsigned short*)(wsb + (1 << 20));      // 256 KB
  unsigned short* w3T  = (unsigned short*)(wsb + (2 << 20));      // 4 MB
  unsigned short* h1   = (unsigned short*)(wsb + (8 << 20));      // 2 MB
  unsigned short* h2   = (unsigned short*)(wsb + (12 << 20));     // 4 MB
  unsigned short* spat = (unsigned short*)(wsb + (16 << 20));     // 32 MB
  float* fl            = (float*)(wsb + (48 << 20));              // 4 MB

  const dim3 blk(256);

  // freq MLP + weight prep (independent of GEMM chain)
  setup_kernel<<<dim3(2576), blk, 0, stream>>>(sW1, sW2, sW3, msg, fW1, fb1,
                                               fW2, fb2, w1T, w2T, w3T, msgb, fl);

  // spatial MLP (bf16 MFMA chain, counted-vmcnt pipelined)
  gemm_mfma<0, 1, 64, 64><<<dim3(32, 2), blk, 0, stream>>>(msgb, w1T, sb1, h1, 256);
  gemm_mfma<0, 1, 256, 128><<<dim3(32, 4), blk, 0, stream>>>(h1, w2T, sb2, h2, 512);
  gemm_mfma<1, 1, 512, 1024><<<dim3(32, 32), blk, 0, stream>>>(h2, w3T, sb3, spat, 4096);

  // upsample + block pattern + depthwise Gaussian
  finalize_kernel<<<dim3(BATCH, 3), blk, 0, stream>>>(msg, fl, spat, out);
}